// Round 7
// baseline (703.604 us; speedup 1.0000x reference)
//
#include <hip/hip_runtime.h>
#include <math.h>

#define N_Q   4096
#define N_DB  65536
#define DIM   32
#define KNN   5
#define NC    64                 // chunks
#define CH    (N_DB / NC)        // 1024 points per chunk
#define TS    256                // staged tile (points)
#define NSTG  (CH / TS)          // 4 stages per chunk
#define NSUB  (TS / 32)          // 8 subtiles per stage
#define NCAND (NC * 6)           // 384 candidates per query
#define BIAS  256.0f

typedef _Float16 half8  __attribute__((ext_vector_type(8)));
typedef __fp16   fp16x2 __attribute__((ext_vector_type(2)));
typedef float floatx16  __attribute__((ext_vector_type(16)));

union H8  { half8 h; uint4 u4; unsigned u[4]; };
union F16 { floatx16 v; float4 q4[4]; float f[16]; unsigned w[16]; };
union HU  { fp16x2 h2; unsigned u; };

__device__ __forceinline__ unsigned cvt2(float a, float b) {
    HU t; t.h2 = __builtin_amdgcn_cvt_pkrtz(a, b);
    return t.u;
}

// ---------------- kernel 1: fused convert + MFMA scan + per-chunk approx top-6 ----------------
// Block: 512 threads (8 waves): 256-query tile x 1024-pt chunk.
// LDS image per buffer: [subtile 0..7][kgroup 0..3][row 0..31][8 halves] (2048 B/subtile)
__global__ __launch_bounds__(512, 8) void k_scan(const float* __restrict__ Q,
                                                 const float* __restrict__ DB,
                                                 unsigned* __restrict__ cand) {
    __shared__ char  dbs[2][16384];    // fp16 db tile, tile-major
    __shared__ float hbs[2][TS];       // C-init: BIAS - 0.5*|d|^2

    const int tid  = threadIdx.x;
    const int lane = tid & 63, w = tid >> 6;          // w = 0..7
    const int h = lane >> 5, qcol = lane & 31;
    const int chunk = blockIdx.x & (NC - 1);          // same-chunk blocks: stride 64 -> same XCD
    const int qb    = blockIdx.x >> 6;                // 0..15
    const int q     = qb * 256 + w * 32 + qcol;
    const int pbase = chunk * CH;

    // staging identity: 2 threads per point (16 dims each)
    const int spt = tid >> 1, shalf = tid & 1;
    const float* sgbase = DB + (size_t)(pbase + spt) * DIM + shalf * 16;

    // ---- issue stage-0 global loads first (overlap with q-prologue) ----
    float4 n0 = *(const float4*)(sgbase + 0);
    float4 n1 = *(const float4*)(sgbase + 4);
    float4 n2 = *(const float4*)(sgbase + 8);
    float4 n3 = *(const float4*)(sgbase + 12);

    // ---- q prologue: pin this lane's query dims as fp16 B-frags ----
    const float* qp = Q + (size_t)q * DIM;
    float4 qa = *(const float4*)(qp + h * 8);
    float4 qb4 = *(const float4*)(qp + h * 8 + 4);
    float4 qc = *(const float4*)(qp + 16 + h * 8);
    float4 qd = *(const float4*)(qp + 16 + h * 8 + 4);
    H8 b1, b2;
    b1.u[0] = cvt2(qa.x, qa.y);  b1.u[1] = cvt2(qa.z, qa.w);
    b1.u[2] = cvt2(qb4.x, qb4.y); b1.u[3] = cvt2(qb4.z, qb4.w);
    b2.u[0] = cvt2(qc.x, qc.y);  b2.u[1] = cvt2(qc.z, qc.w);
    b2.u[2] = cvt2(qd.x, qd.y);  b2.u[3] = cvt2(qd.z, qd.w);

    auto stage_finish = [&](int buf, float4 f0, float4 f1, float4 f2, float4 f3) {
        float s = f0.x*f0.x + f0.y*f0.y + f0.z*f0.z + f0.w*f0.w
                + f1.x*f1.x + f1.y*f1.y + f1.z*f1.z + f1.w*f1.w
                + f2.x*f2.x + f2.y*f2.y + f2.z*f2.z + f2.w*f2.w
                + f3.x*f3.x + f3.y*f3.y + f3.z*f3.z + f3.w*f3.w;
        s += __shfl_xor(s, 1, 64);                    // pair covers the other 16 dims
        if (shalf == 0) hbs[buf][spt] = BIAS - 0.5f * s;
        uint4 ua, ub;
        ua.x = cvt2(f0.x, f0.y); ua.y = cvt2(f0.z, f0.w);
        ua.z = cvt2(f1.x, f1.y); ua.w = cvt2(f1.z, f1.w);
        ub.x = cvt2(f2.x, f2.y); ub.y = cvt2(f2.z, f2.w);
        ub.z = cvt2(f3.x, f3.y); ub.w = cvt2(f3.z, f3.w);
        char* base = dbs[buf] + (spt >> 5) * 2048 + (shalf * 2) * 512 + (spt & 31) * 16;
        *(uint4*)(base)       = ua;                   // kgroup shalf*2
        *(uint4*)(base + 512) = ub;                   // kgroup shalf*2+1
    };

    stage_finish(0, n0, n1, n2, n3);

    float tk[6];                                      // packed top-6 (descending, positive)
#pragma unroll
    for (int r = 0; r < 6; ++r) tk[r] = 0.f;

    constexpr int ROWC[16] = {0,1,2,3, 8,9,10,11, 16,17,18,19, 24,25,26,27}; // bit 2 = h

    for (int t = 0; t < NSTG; ++t) {
        __syncthreads();                              // buf(t) writes visible; buf(t^1) free
        if (t + 1 < NSTG) {                           // issue next stage's loads early
            const float* g = sgbase + (size_t)(t + 1) * TS * DIM;
            n0 = *(const float4*)(g + 0);  n1 = *(const float4*)(g + 4);
            n2 = *(const float4*)(g + 8);  n3 = *(const float4*)(g + 12);
        }
        const int buf = t & 1;
        const char* base = dbs[buf];
#pragma unroll
        for (int sub = 0; sub < NSUB; ++sub) {
            const char* tb = base + sub * 2048;
            H8 a1, a2;
            a1.u4 = *(const uint4*)(tb + h * 512 + (lane & 31) * 16);
            a2.u4 = *(const uint4*)(tb + 1024 + h * 512 + (lane & 31) * 16);
            F16 c0;
            const float* hb = &hbs[buf][sub * 32 + 4 * h];
            c0.q4[0] = *(const float4*)(hb + 0);
            c0.q4[1] = *(const float4*)(hb + 8);
            c0.q4[2] = *(const float4*)(hb + 16);
            c0.q4[3] = *(const float4*)(hb + 24);
            floatx16 acc = __builtin_amdgcn_mfma_f32_32x32x16_f16(a1.h, b1.h, c0.v, 0, 0, 0);
            acc = __builtin_amdgcn_mfma_f32_32x32x16_f16(a2.h, b2.h, acc, 0, 0, 0);
            // pack 10-bit chunk-local id into CLEARED low mantissa bits
            F16 pk; pk.v = acc;
            const unsigned meta = (unsigned)(((t * NSUB + sub) << 5) | (h << 2));
            float p[16];
#pragma unroll
            for (int r = 0; r < 16; ++r)
                p[r] = __uint_as_float((pk.w[r] & 0xFFFFFC00u) | meta | (unsigned)ROWC[r]);
            // true top-2 of 16 (max/min tournament)
            float hi[8], lo[8];
#pragma unroll
            for (int i = 0; i < 8; ++i) { hi[i] = fmaxf(p[2*i], p[2*i+1]); lo[i] = fminf(p[2*i], p[2*i+1]); }
            float H4[4], L4[4];
#pragma unroll
            for (int i = 0; i < 4; ++i) {
                H4[i] = fmaxf(hi[2*i], hi[2*i+1]);
                L4[i] = fmaxf(fmaxf(lo[2*i], lo[2*i+1]), fminf(hi[2*i], hi[2*i+1]));
            }
            float H2[2], L2[2];
#pragma unroll
            for (int i = 0; i < 2; ++i) {
                H2[i] = fmaxf(H4[2*i], H4[2*i+1]);
                L2[i] = fmaxf(fmaxf(L4[2*i], L4[2*i+1]), fminf(H4[2*i], H4[2*i+1]));
            }
            float c1 = fmaxf(H2[0], H2[1]);
            float c2 = fmaxf(fmaxf(L2[0], L2[1]), fminf(H2[0], H2[1]));
            // branchless sorted-6 insert (c1 first; c2 can't land at slot 0)
#pragma unroll
            for (int i = 0; i < 6; ++i) { float mx = fmaxf(tk[i], c1); c1 = fminf(tk[i], c1); tk[i] = mx; }
#pragma unroll
            for (int i = 1; i < 6; ++i) { float mx = fmaxf(tk[i], c2); c2 = fminf(tk[i], c2); tk[i] = mx; }
        }
        if (t + 1 < NSTG) stage_finish((t + 1) & 1, n0, n1, n2, n3);
    }

    // merge the two half-lane streams (same query, disjoint rows).
    // R6 BUG FIX: snapshot the partner's list BEFORE mutating tk — fused
    // shfl+merge read partially-merged partner state (dup/drop candidates).
    float other[6];
#pragma unroll
    for (int i = 0; i < 6; ++i) other[i] = __shfl_xor(tk[i], 32, 64);
#pragma unroll
    for (int i = 0; i < 6; ++i) {
        float val = other[i];
#pragma unroll
        for (int j = 0; j < 6; ++j) { float mx = fmaxf(tk[j], val); val = fminf(tk[j], val); tk[j] = mx; }
    }
    if (h == 0) {
        unsigned* dst = cand + ((size_t)q * NC + chunk) * 6;
#pragma unroll
        for (int r = 0; r < 6; ++r) dst[r] = __float_as_uint(tk[r]);
    }
}

// ---------------- kernel 2: global approx top-12, exact rescore, top-5, blend ----------------
__global__ __launch_bounds__(256) void k_merge(const float* __restrict__ Q,
                                               const float* __restrict__ DB,
                                               const float* __restrict__ AUX,
                                               const unsigned* __restrict__ cand,
                                               float* __restrict__ out) {
    const int tid = threadIdx.x, lane = tid & 63, w = tid >> 6;
    const int q = blockIdx.x * 4 + w;

    // lane = chunk; its 6 candidates arrive already sorted descending
    const unsigned* cq = cand + (size_t)q * NCAND + (size_t)lane * 6;
    float cur[6];
#pragma unroll
    for (int r = 0; r < 6; ++r) cur[r] = __uint_as_float(cq[r]);

    float wv[12]; int wl[12];
#pragma unroll
    for (int r = 0; r < 12; ++r) {
        float bv = cur[0]; int bl = lane;
#pragma unroll
        for (int off = 32; off >= 1; off >>= 1) {
            float ov = __shfl_xor(bv, off, 64);
            int   ol = __shfl_xor(bl, off, 64);
            if (ov > bv || (ov == bv && ol < bl)) { bv = ov; bl = ol; }
        }
        wv[r] = bv; wl[r] = bl;
        if (bl == lane) {                             // winner pops its head
#pragma unroll
            for (int s = 0; s < 5; ++s) cur[s] = cur[s + 1];
            cur[5] = -1.f;
        }
    }

    // exact fp32 rescore of the 12 (lanes 0..11)
    float dist = 1e30f; int dbi = 0x7fffffff;
    if (lane < 12) {
        unsigned u = __float_as_uint(wv[lane]) & 1023u;   // chunk-local point id
        dbi = wl[lane] * CH + (int)u;
        const float4* dp = (const float4*)(DB + (size_t)dbi * DIM);
        const float4* qp = (const float4*)(Q + (size_t)q * DIM);
        float dot = 0.f, qs = 0.f, ds = 0.f;
#pragma unroll
        for (int j = 0; j < DIM / 4; ++j) {
            float4 a = qp[j], d = dp[j];
            dot += a.x * d.x + a.y * d.y + a.z * d.z + a.w * d.w;
            qs  += a.x * a.x + a.y * a.y + a.z * a.z + a.w * a.w;
            ds  += d.x * d.x + d.y * d.y + d.z * d.z + d.w * d.w;
        }
        dist = sqrtf(fmaxf(qs + ds - 2.f * dot, 0.f));
    }
    // exact top-5 by (dist, smaller index) — matches reference tie-break
    float wd[KNN]; int wi[KNN];
#pragma unroll
    for (int r = 0; r < KNN; ++r) {
        float bd = dist; int bi = dbi;
#pragma unroll
        for (int off = 32; off >= 1; off >>= 1) {
            float od = __shfl_xor(bd, off, 64);
            int   oi = __shfl_xor(bi, off, 64);
            if (od < bd || (od == bd && oi < bi)) { bd = od; bi = oi; }
        }
        wd[r] = bd; wi[r] = bi;
        if (dist == bd && dbi == bi) dist = 1e30f;
    }
    float ww[KNN], W = 0.f;
#pragma unroll
    for (int r = 0; r < KNN; ++r) { ww[r] = 1.f / (wd[r] + 1e-6f); W += ww[r]; }
    if (lane < DIM) {
        float o = 0.f;
#pragma unroll
        for (int r = 0; r < KNN; ++r) o += ww[r] * AUX[(size_t)wi[r] * DIM + lane];
        out[(size_t)q * DIM + lane] = o / W;
    }
}

// ---------------- launch ----------------
extern "C" void kernel_launch(void* const* d_in, const int* in_sizes, int n_in,
                              void* d_out, int out_size, void* d_ws, size_t ws_size,
                              hipStream_t stream) {
    const float* Q   = (const float*)d_in[0];
    const float* DB  = (const float*)d_in[1];
    const float* AUX = (const float*)d_in[2];
    float* out = (float*)d_out;

    unsigned* cand = (unsigned*)d_ws;                 // 4096*384*4 = 6 MB

    k_scan<<<(N_Q / 256) * NC, 512, 0, stream>>>(Q, DB, cand);
    k_merge<<<N_Q / 4, 256, 0, stream>>>(Q, DB, AUX, cand, out);
}

// Round 8
// 152.815 us; speedup vs baseline: 4.6043x; 4.6043x over previous
//
#include <hip/hip_runtime.h>
#include <math.h>

#define N_Q   4096
#define N_DB  65536
#define DIM   32
#define KNN   5
#define NC    64                 // chunks
#define CH    (N_DB / NC)        // 1024 points per chunk
#define TS    256                // staged tile (points)
#define NSTG  (CH / TS)          // 4 stages per chunk
#define NSUB  (TS / 32)          // 8 subtiles per stage
#define NCAND (NC * 6)           // 384 candidates per query
#define BIAS  256.0f

typedef _Float16 half8  __attribute__((ext_vector_type(8)));
typedef __fp16   fp16x2 __attribute__((ext_vector_type(2)));
typedef float floatx16  __attribute__((ext_vector_type(16)));

union H8  { half8 h; uint4 u4; unsigned u[4]; };
union F16 { floatx16 v; float4 q4[4]; float f[16]; unsigned w[16]; };
union HU  { fp16x2 h2; unsigned u; };

__device__ __forceinline__ unsigned cvt2(float a, float b) {
    HU t; t.h2 = __builtin_amdgcn_cvt_pkrtz(a, b);
    return t.u;
}

// ---------------- kernel 1: fused convert + MFMA scan + per-chunk approx top-6 ----------------
// Block: 512 threads (8 waves): 256-query tile x 1024-pt chunk.
// LDS image per buffer: [subtile 0..7][kgroup 0..3][row 0..31][8 halves] (2048 B/subtile)
// launch_bounds(512, 2): R7 used (512,8) -> allocator capped at 32 VGPR -> 2.3 GB
// scratch spill traffic, 626 us. (512,2) leaves >=128 VGPR headroom; kernel
// needs ~80 live regs; LDS (34 KB) limits to 4 blocks/CU anyway.
__global__ __launch_bounds__(512, 2) void k_scan(const float* __restrict__ Q,
                                                 const float* __restrict__ DB,
                                                 unsigned* __restrict__ cand) {
    __shared__ char  dbs[2][16384];    // fp16 db tile, tile-major
    __shared__ float hbs[2][TS];       // C-init: BIAS - 0.5*|d|^2

    const int tid  = threadIdx.x;
    const int lane = tid & 63, w = tid >> 6;          // w = 0..7
    const int h = lane >> 5, qcol = lane & 31;
    const int chunk = blockIdx.x & (NC - 1);          // same-chunk blocks: stride 64 -> same XCD
    const int qb    = blockIdx.x >> 6;                // 0..15
    const int q     = qb * 256 + w * 32 + qcol;
    const int pbase = chunk * CH;

    // staging identity: 2 threads per point (16 dims each)
    const int spt = tid >> 1, shalf = tid & 1;
    const float* sgbase = DB + (size_t)(pbase + spt) * DIM + shalf * 16;

    // ---- issue stage-0 global loads first (overlap with q-prologue) ----
    float4 n0 = *(const float4*)(sgbase + 0);
    float4 n1 = *(const float4*)(sgbase + 4);
    float4 n2 = *(const float4*)(sgbase + 8);
    float4 n3 = *(const float4*)(sgbase + 12);

    // ---- q prologue: pin this lane's query dims as fp16 B-frags ----
    const float* qp = Q + (size_t)q * DIM;
    float4 qa = *(const float4*)(qp + h * 8);
    float4 qb4 = *(const float4*)(qp + h * 8 + 4);
    float4 qc = *(const float4*)(qp + 16 + h * 8);
    float4 qd = *(const float4*)(qp + 16 + h * 8 + 4);
    H8 b1, b2;
    b1.u[0] = cvt2(qa.x, qa.y);  b1.u[1] = cvt2(qa.z, qa.w);
    b1.u[2] = cvt2(qb4.x, qb4.y); b1.u[3] = cvt2(qb4.z, qb4.w);
    b2.u[0] = cvt2(qc.x, qc.y);  b2.u[1] = cvt2(qc.z, qc.w);
    b2.u[2] = cvt2(qd.x, qd.y);  b2.u[3] = cvt2(qd.z, qd.w);

    auto stage_finish = [&](int buf, float4 f0, float4 f1, float4 f2, float4 f3) {
        float s = f0.x*f0.x + f0.y*f0.y + f0.z*f0.z + f0.w*f0.w
                + f1.x*f1.x + f1.y*f1.y + f1.z*f1.z + f1.w*f1.w
                + f2.x*f2.x + f2.y*f2.y + f2.z*f2.z + f2.w*f2.w
                + f3.x*f3.x + f3.y*f3.y + f3.z*f3.z + f3.w*f3.w;
        s += __shfl_xor(s, 1, 64);                    // pair covers the other 16 dims
        if (shalf == 0) hbs[buf][spt] = BIAS - 0.5f * s;
        uint4 ua, ub;
        ua.x = cvt2(f0.x, f0.y); ua.y = cvt2(f0.z, f0.w);
        ua.z = cvt2(f1.x, f1.y); ua.w = cvt2(f1.z, f1.w);
        ub.x = cvt2(f2.x, f2.y); ub.y = cvt2(f2.z, f2.w);
        ub.z = cvt2(f3.x, f3.y); ub.w = cvt2(f3.z, f3.w);
        char* base = dbs[buf] + (spt >> 5) * 2048 + (shalf * 2) * 512 + (spt & 31) * 16;
        *(uint4*)(base)       = ua;                   // kgroup shalf*2
        *(uint4*)(base + 512) = ub;                   // kgroup shalf*2+1
    };

    stage_finish(0, n0, n1, n2, n3);

    float tk[6];                                      // packed top-6 (descending, positive)
#pragma unroll
    for (int r = 0; r < 6; ++r) tk[r] = 0.f;

    constexpr int ROWC[16] = {0,1,2,3, 8,9,10,11, 16,17,18,19, 24,25,26,27}; // bit 2 = h

    for (int t = 0; t < NSTG; ++t) {
        __syncthreads();                              // buf(t) writes visible; buf(t^1) free
        if (t + 1 < NSTG) {                           // issue next stage's loads early
            const float* g = sgbase + (size_t)(t + 1) * TS * DIM;
            n0 = *(const float4*)(g + 0);  n1 = *(const float4*)(g + 4);
            n2 = *(const float4*)(g + 8);  n3 = *(const float4*)(g + 12);
        }
        const int buf = t & 1;
        const char* base = dbs[buf];
#pragma unroll
        for (int sub = 0; sub < NSUB; ++sub) {
            const char* tb = base + sub * 2048;
            H8 a1, a2;
            a1.u4 = *(const uint4*)(tb + h * 512 + (lane & 31) * 16);
            a2.u4 = *(const uint4*)(tb + 1024 + h * 512 + (lane & 31) * 16);
            F16 c0;
            const float* hb = &hbs[buf][sub * 32 + 4 * h];
            c0.q4[0] = *(const float4*)(hb + 0);
            c0.q4[1] = *(const float4*)(hb + 8);
            c0.q4[2] = *(const float4*)(hb + 16);
            c0.q4[3] = *(const float4*)(hb + 24);
            floatx16 acc = __builtin_amdgcn_mfma_f32_32x32x16_f16(a1.h, b1.h, c0.v, 0, 0, 0);
            acc = __builtin_amdgcn_mfma_f32_32x32x16_f16(a2.h, b2.h, acc, 0, 0, 0);
            // pack 10-bit chunk-local id into CLEARED low mantissa bits
            F16 pk; pk.v = acc;
            const unsigned meta = (unsigned)(((t * NSUB + sub) << 5) | (h << 2));
            float p[16];
#pragma unroll
            for (int r = 0; r < 16; ++r)
                p[r] = __uint_as_float((pk.w[r] & 0xFFFFFC00u) | meta | (unsigned)ROWC[r]);
            // true top-2 of 16 (max/min tournament)
            float hi[8], lo[8];
#pragma unroll
            for (int i = 0; i < 8; ++i) { hi[i] = fmaxf(p[2*i], p[2*i+1]); lo[i] = fminf(p[2*i], p[2*i+1]); }
            float H4[4], L4[4];
#pragma unroll
            for (int i = 0; i < 4; ++i) {
                H4[i] = fmaxf(hi[2*i], hi[2*i+1]);
                L4[i] = fmaxf(fmaxf(lo[2*i], lo[2*i+1]), fminf(hi[2*i], hi[2*i+1]));
            }
            float H2[2], L2[2];
#pragma unroll
            for (int i = 0; i < 2; ++i) {
                H2[i] = fmaxf(H4[2*i], H4[2*i+1]);
                L2[i] = fmaxf(fmaxf(L4[2*i], L4[2*i+1]), fminf(H4[2*i], H4[2*i+1]));
            }
            float c1 = fmaxf(H2[0], H2[1]);
            float c2 = fmaxf(fmaxf(L2[0], L2[1]), fminf(H2[0], H2[1]));
            // branchless sorted-6 insert (c1 first; c2 can't land at slot 0)
#pragma unroll
            for (int i = 0; i < 6; ++i) { float mx = fmaxf(tk[i], c1); c1 = fminf(tk[i], c1); tk[i] = mx; }
#pragma unroll
            for (int i = 1; i < 6; ++i) { float mx = fmaxf(tk[i], c2); c2 = fminf(tk[i], c2); tk[i] = mx; }
        }
        if (t + 1 < NSTG) stage_finish((t + 1) & 1, n0, n1, n2, n3);
    }

    // merge the two half-lane streams (same query, disjoint rows).
    // snapshot the partner's list BEFORE mutating tk (R6 hazard fix).
    float other[6];
#pragma unroll
    for (int i = 0; i < 6; ++i) other[i] = __shfl_xor(tk[i], 32, 64);
#pragma unroll
    for (int i = 0; i < 6; ++i) {
        float val = other[i];
#pragma unroll
        for (int j = 0; j < 6; ++j) { float mx = fmaxf(tk[j], val); val = fminf(tk[j], val); tk[j] = mx; }
    }
    if (h == 0) {
        unsigned* dst = cand + ((size_t)q * NC + chunk) * 6;
#pragma unroll
        for (int r = 0; r < 6; ++r) dst[r] = __float_as_uint(tk[r]);
    }
}

// ---------------- kernel 2: global approx top-12, exact rescore, top-5, blend ----------------
__global__ __launch_bounds__(256) void k_merge(const float* __restrict__ Q,
                                               const float* __restrict__ DB,
                                               const float* __restrict__ AUX,
                                               const unsigned* __restrict__ cand,
                                               float* __restrict__ out) {
    const int tid = threadIdx.x, lane = tid & 63, w = tid >> 6;
    const int q = blockIdx.x * 4 + w;

    // lane = chunk; its 6 candidates arrive already sorted descending
    const unsigned* cq = cand + (size_t)q * NCAND + (size_t)lane * 6;
    float cur[6];
#pragma unroll
    for (int r = 0; r < 6; ++r) cur[r] = __uint_as_float(cq[r]);

    float wv[12]; int wl[12];
#pragma unroll
    for (int r = 0; r < 12; ++r) {
        float bv = cur[0]; int bl = lane;
#pragma unroll
        for (int off = 32; off >= 1; off >>= 1) {
            float ov = __shfl_xor(bv, off, 64);
            int   ol = __shfl_xor(bl, off, 64);
            if (ov > bv || (ov == bv && ol < bl)) { bv = ov; bl = ol; }
        }
        wv[r] = bv; wl[r] = bl;
        if (bl == lane) {                             // winner pops its head
#pragma unroll
            for (int s = 0; s < 5; ++s) cur[s] = cur[s + 1];
            cur[5] = -1.f;
        }
    }

    // exact fp32 rescore of the 12 (lanes 0..11)
    float dist = 1e30f; int dbi = 0x7fffffff;
    if (lane < 12) {
        unsigned u = __float_as_uint(wv[lane]) & 1023u;   // chunk-local point id
        dbi = wl[lane] * CH + (int)u;
        const float4* dp = (const float4*)(DB + (size_t)dbi * DIM);
        const float4* qp = (const float4*)(Q + (size_t)q * DIM);
        float dot = 0.f, qs = 0.f, ds = 0.f;
#pragma unroll
        for (int j = 0; j < DIM / 4; ++j) {
            float4 a = qp[j], d = dp[j];
            dot += a.x * d.x + a.y * d.y + a.z * d.z + a.w * d.w;
            qs  += a.x * a.x + a.y * a.y + a.z * a.z + a.w * a.w;
            ds  += d.x * d.x + d.y * d.y + d.z * d.z + d.w * d.w;
        }
        dist = sqrtf(fmaxf(qs + ds - 2.f * dot, 0.f));
    }
    // exact top-5 by (dist, smaller index) — matches reference tie-break
    float wd[KNN]; int wi[KNN];
#pragma unroll
    for (int r = 0; r < KNN; ++r) {
        float bd = dist; int bi = dbi;
#pragma unroll
        for (int off = 32; off >= 1; off >>= 1) {
            float od = __shfl_xor(bd, off, 64);
            int   oi = __shfl_xor(bi, off, 64);
            if (od < bd || (od == bd && oi < bi)) { bd = od; bi = oi; }
        }
        wd[r] = bd; wi[r] = bi;
        if (dist == bd && dbi == bi) dist = 1e30f;
    }
    float ww[KNN], W = 0.f;
#pragma unroll
    for (int r = 0; r < KNN; ++r) { ww[r] = 1.f / (wd[r] + 1e-6f); W += ww[r]; }
    if (lane < DIM) {
        float o = 0.f;
#pragma unroll
        for (int r = 0; r < KNN; ++r) o += ww[r] * AUX[(size_t)wi[r] * DIM + lane];
        out[(size_t)q * DIM + lane] = o / W;
    }
}

// ---------------- launch ----------------
extern "C" void kernel_launch(void* const* d_in, const int* in_sizes, int n_in,
                              void* d_out, int out_size, void* d_ws, size_t ws_size,
                              hipStream_t stream) {
    const float* Q   = (const float*)d_in[0];
    const float* DB  = (const float*)d_in[1];
    const float* AUX = (const float*)d_in[2];
    float* out = (float*)d_out;

    unsigned* cand = (unsigned*)d_ws;                 // 4096*384*4 = 6 MB

    k_scan<<<(N_Q / 256) * NC, 512, 0, stream>>>(Q, DB, cand);
    k_merge<<<N_Q / 4, 256, 0, stream>>>(Q, DB, AUX, cand, out);
}

// Round 9
// 138.862 us; speedup vs baseline: 5.0669x; 1.1005x over previous
//
#include <hip/hip_runtime.h>
#include <math.h>

#define N_Q   4096
#define N_DB  65536
#define DIM   32
#define KNN   5
#define NC    64                 // chunks
#define CH    (N_DB / NC)        // 1024 points per chunk
#define TS    128                // staged tile (points)
#define NSTG  (CH / TS)          // 8 stages per chunk
#define NSUB  (TS / 32)          // 4 subtiles per stage
#define NCAND (NC * 6)           // 384 candidates per query
#define BIAS  256.0f

typedef _Float16 half8  __attribute__((ext_vector_type(8)));
typedef __fp16   fp16x2 __attribute__((ext_vector_type(2)));
typedef float floatx16  __attribute__((ext_vector_type(16)));

union H8  { half8 h; uint4 u4; unsigned u[4]; };
union F16 { floatx16 v; float4 q4[4]; unsigned w[16]; };
union HU  { fp16x2 h2; unsigned u; };

__device__ __forceinline__ unsigned cvt2(float a, float b) {
    HU t; t.h2 = __builtin_amdgcn_cvt_pkrtz(a, b);
    return t.u;
}

__device__ __forceinline__ void ld_lds16(const void* g, void* l) {
    __builtin_amdgcn_global_load_lds((const __attribute__((address_space(1))) unsigned*)g,
                                     (__attribute__((address_space(3))) unsigned*)l, 16, 0, 0);
}
__device__ __forceinline__ void ld_lds4(const void* g, void* l) {
    __builtin_amdgcn_global_load_lds((const __attribute__((address_space(1))) unsigned*)g,
                                     (__attribute__((address_space(3))) unsigned*)l, 4, 0, 0);
}

// ---------------- kernel 0: fp32 db -> tile-major fp16 image + biased norms ----------------
// DBh: [tile=p>>5][kgroup 0..3][row=p&31][8 halves]  (2 KB per 32-pt tile)
__global__ __launch_bounds__(256) void k_prep(const float* __restrict__ DB,
                                              uint4* __restrict__ DBh,
                                              float* __restrict__ hdb) {
    int p = blockIdx.x * 256 + threadIdx.x;
    const float4* src = (const float4*)(DB + (size_t)p * DIM);
    float4 f[8]; float s = 0.f;
#pragma unroll
    for (int j = 0; j < 8; ++j) {
        f[j] = src[j];
        s += f[j].x * f[j].x + f[j].y * f[j].y + f[j].z * f[j].z + f[j].w * f[j].w;
    }
    hdb[p] = BIAS - 0.5f * s;
    int t = p >> 5, r = p & 31;
#pragma unroll
    for (int gi = 0; gi < 4; ++gi) {
        uint4 g;
        g.x = cvt2(f[2 * gi].x, f[2 * gi].y);
        g.y = cvt2(f[2 * gi].z, f[2 * gi].w);
        g.z = cvt2(f[2 * gi + 1].x, f[2 * gi + 1].y);
        g.w = cvt2(f[2 * gi + 1].z, f[2 * gi + 1].w);
        DBh[(size_t)t * 128 + gi * 32 + r] = g;
    }
}

// ---------------- kernel 1: MFMA scan + per-chunk approx top-6 ----------------
// 256 threads (4 waves) = 128-query tile x 1024-pt chunk; grid 32 x 64 = 2048 blocks.
// LDS 17 KB -> up to 9 blocks/CU; launch_bounds(256,4) = min-BLOCKS/CU semantics
// (R7 lesson), caps VGPR at 128 (no spill) while allowing natural 7-8 blocks/CU.
__global__ __launch_bounds__(256, 4) void k_scan(const float* __restrict__ Q,
                                                 const uint4* __restrict__ DBh,
                                                 const float* __restrict__ hdb,
                                                 unsigned* __restrict__ cand) {
    __shared__ char  dbs[2][8192];     // fp16 db stage (4 subtiles x 2 KB)
    __shared__ float hbs[2][TS];       // C-init values

    const int tid = threadIdx.x, lane = tid & 63, w = tid >> 6;   // w=0..3
    const int h = lane >> 5, qcol = lane & 31;
    const int chunk = blockIdx.x & (NC - 1);   // same-chunk blocks: stride 64 -> same XCD
    const int qb    = blockIdx.x >> 6;         // 0..31
    const int q     = qb * 128 + w * 32 + qcol;
    const int pbase = chunk * CH;

    // B-frags: convert this lane's query dims once
    const float* qp = Q + (size_t)q * DIM;
    float4 qa = *(const float4*)(qp + h * 8);
    float4 qb4 = *(const float4*)(qp + h * 8 + 4);
    float4 qc = *(const float4*)(qp + 16 + h * 8);
    float4 qd = *(const float4*)(qp + 16 + h * 8 + 4);
    H8 b1, b2;
    b1.u[0] = cvt2(qa.x, qa.y);   b1.u[1] = cvt2(qa.z, qa.w);
    b1.u[2] = cvt2(qb4.x, qb4.y); b1.u[3] = cvt2(qb4.z, qb4.w);
    b2.u[0] = cvt2(qc.x, qc.y);   b2.u[1] = cvt2(qc.z, qc.w);
    b2.u[2] = cvt2(qd.x, qd.y);   b2.u[3] = cvt2(qd.z, qd.w);

    // opaque VGPR mask -> pack is a single v_and_or_b32 (S2 = scalar id)
    unsigned maskv;
    asm("v_mov_b32 %0, 0xFFFFFC00" : "=v"(maskv));

    auto stage = [&](int buf, int t) {
        const char* s = (const char*)DBh + (size_t)pbase * 64 + (size_t)t * 8192
                        + w * 1024 + lane * 16;
        char* d = dbs[buf] + w * 1024;            // wave-uniform base; HW adds lane*16
        ld_lds16(s, d);
        ld_lds16(s + 4096, d + 4096);
        if (w < 2)                                 // waves 0,1 stage the 128 C-init floats
            ld_lds4(hdb + pbase + t * TS + w * 64 + lane,
                    (char*)&hbs[buf][0] + w * 256);
    };

    float tk[6];
#pragma unroll
    for (int r = 0; r < 6; ++r) tk[r] = 0.f;

    constexpr int ROWC[16] = {0,1,2,3, 8,9,10,11, 16,17,18,19, 24,25,26,27}; // bit 2 free (=h)

    stage(0, 0);
    for (int t = 0; t < NSTG; ++t) {
        __syncthreads();                           // drains buf(t) loads (issued a stage ago)
        if (t + 1 < NSTG) stage((t + 1) & 1, t + 1);
        const int buf = t & 1;
        const char* base = dbs[buf];
#pragma unroll
        for (int sub = 0; sub < NSUB; ++sub) {
            const char* tb = base + sub * 2048;
            H8 a1, a2;
            a1.u4 = *(const uint4*)(tb + h * 512 + (lane & 31) * 16);
            a2.u4 = *(const uint4*)(tb + 1024 + h * 512 + (lane & 31) * 16);
            F16 c0;
            const float* hb = &hbs[buf][sub * 32 + 4 * h];
            c0.q4[0] = *(const float4*)(hb + 0);
            c0.q4[1] = *(const float4*)(hb + 8);
            c0.q4[2] = *(const float4*)(hb + 16);
            c0.q4[3] = *(const float4*)(hb + 24);
            floatx16 acc = __builtin_amdgcn_mfma_f32_32x32x16_f16(a1.h, b1.h, c0.v, 0, 0, 0);
            acc = __builtin_amdgcn_mfma_f32_32x32x16_f16(a2.h, b2.h, acc, 0, 0, 0);
            // pack 10-bit chunk-local id (tile<<5 | rowc); h bit is OR-ed at chunk end
            F16 pk; pk.v = acc;
            const int meta = (t * NSUB + sub) << 5;      // wave-uniform (scalar pipe)
            float p[16];
#pragma unroll
            for (int r = 0; r < 16; ++r)
                p[r] = __uint_as_float((pk.w[r] & maskv) | (unsigned)(meta | ROWC[r]));
            // true top-2 of 16 (max/min tournament; L-combines fold to v_max3)
            float hi[8], lo[8];
#pragma unroll
            for (int i = 0; i < 8; ++i) { hi[i] = fmaxf(p[2*i], p[2*i+1]); lo[i] = fminf(p[2*i], p[2*i+1]); }
            float H4[4], L4[4];
#pragma unroll
            for (int i = 0; i < 4; ++i) {
                H4[i] = fmaxf(hi[2*i], hi[2*i+1]);
                L4[i] = fmaxf(fmaxf(lo[2*i], lo[2*i+1]), fminf(hi[2*i], hi[2*i+1]));
            }
            float H2[2], L2[2];
#pragma unroll
            for (int i = 0; i < 2; ++i) {
                H2[i] = fmaxf(H4[2*i], H4[2*i+1]);
                L2[i] = fmaxf(fmaxf(L4[2*i], L4[2*i+1]), fminf(H4[2*i], H4[2*i+1]));
            }
            float c1 = fmaxf(H2[0], H2[1]);
            float c2 = fmaxf(fmaxf(L2[0], L2[1]), fminf(H2[0], H2[1]));
            // branchless sorted-6 insert (c1 >= c2; c2 can't land at slot 0)
#pragma unroll
            for (int i = 0; i < 6; ++i) { float mx = fmaxf(tk[i], c1); c1 = fminf(tk[i], c1); tk[i] = mx; }
#pragma unroll
            for (int i = 1; i < 6; ++i) { float mx = fmaxf(tk[i], c2); c2 = fminf(tk[i], c2); tk[i] = mx; }
        }
    }

    // set the h bit (bit 2 of id field) on the 6 survivors, once per chunk
#pragma unroll
    for (int r = 0; r < 6; ++r)
        tk[r] = __uint_as_float(__float_as_uint(tk[r]) | (unsigned)(h << 2));

    // cross-half merge: SNAPSHOT partner's list before mutating (R6 hazard fix)
    float other[6];
#pragma unroll
    for (int i = 0; i < 6; ++i) other[i] = __shfl_xor(tk[i], 32, 64);
#pragma unroll
    for (int i = 0; i < 6; ++i) {
        float val = other[i];
#pragma unroll
        for (int j = 0; j < 6; ++j) { float mx = fmaxf(tk[j], val); val = fminf(tk[j], val); tk[j] = mx; }
    }
    if (h == 0) {
        unsigned* dst = cand + ((size_t)q * NC + chunk) * 6;
#pragma unroll
        for (int r = 0; r < 6; ++r) dst[r] = __float_as_uint(tk[r]);
    }
}

// ---------------- kernel 2: global approx top-12, exact rescore, top-5, blend ----------------
__global__ __launch_bounds__(256) void k_merge(const float* __restrict__ Q,
                                               const float* __restrict__ DB,
                                               const float* __restrict__ AUX,
                                               const unsigned* __restrict__ cand,
                                               float* __restrict__ out) {
    const int tid = threadIdx.x, lane = tid & 63, w = tid >> 6;
    const int q = blockIdx.x * 4 + w;

    const unsigned* cq = cand + (size_t)q * NCAND + (size_t)lane * 6;
    float cur[6];
#pragma unroll
    for (int r = 0; r < 6; ++r) cur[r] = __uint_as_float(cq[r]);

    float wv[12]; int wl[12];
#pragma unroll
    for (int r = 0; r < 12; ++r) {
        float bv = cur[0]; int bl = lane;
#pragma unroll
        for (int off = 32; off >= 1; off >>= 1) {
            float ov = __shfl_xor(bv, off, 64);
            int   ol = __shfl_xor(bl, off, 64);
            if (ov > bv || (ov == bv && ol < bl)) { bv = ov; bl = ol; }
        }
        wv[r] = bv; wl[r] = bl;
        if (bl == lane) {
#pragma unroll
            for (int s = 0; s < 5; ++s) cur[s] = cur[s + 1];
            cur[5] = -1.f;
        }
    }

    float dist = 1e30f; int dbi = 0x7fffffff;
    if (lane < 12) {
        unsigned u = __float_as_uint(wv[lane]) & 1023u;   // chunk-local point id
        dbi = wl[lane] * CH + (int)u;
        const float4* dp = (const float4*)(DB + (size_t)dbi * DIM);
        const float4* qp = (const float4*)(Q + (size_t)q * DIM);
        float dot = 0.f, qs = 0.f, ds = 0.f;
#pragma unroll
        for (int j = 0; j < DIM / 4; ++j) {
            float4 a = qp[j], d = dp[j];
            dot += a.x * d.x + a.y * d.y + a.z * d.z + a.w * d.w;
            qs  += a.x * a.x + a.y * a.y + a.z * a.z + a.w * a.w;
            ds  += d.x * d.x + d.y * d.y + d.z * d.z + d.w * d.w;
        }
        dist = sqrtf(fmaxf(qs + ds - 2.f * dot, 0.f));
    }
    float wd[KNN]; int wi[KNN];
#pragma unroll
    for (int r = 0; r < KNN; ++r) {
        float bd = dist; int bi = dbi;
#pragma unroll
        for (int off = 32; off >= 1; off >>= 1) {
            float od = __shfl_xor(bd, off, 64);
            int   oi = __shfl_xor(bi, off, 64);
            if (od < bd || (od == bd && oi < bi)) { bd = od; bi = oi; }
        }
        wd[r] = bd; wi[r] = bi;
        if (dist == bd && dbi == bi) dist = 1e30f;
    }
    float ww[KNN], W = 0.f;
#pragma unroll
    for (int r = 0; r < KNN; ++r) { ww[r] = 1.f / (wd[r] + 1e-6f); W += ww[r]; }
    if (lane < DIM) {
        float o = 0.f;
#pragma unroll
        for (int r = 0; r < KNN; ++r) o += ww[r] * AUX[(size_t)wi[r] * DIM + lane];
        out[(size_t)q * DIM + lane] = o / W;
    }
}

// ---------------- launch ----------------
extern "C" void kernel_launch(void* const* d_in, const int* in_sizes, int n_in,
                              void* d_out, int out_size, void* d_ws, size_t ws_size,
                              hipStream_t stream) {
    const float* Q   = (const float*)d_in[0];
    const float* DB  = (const float*)d_in[1];
    const float* AUX = (const float*)d_in[2];
    float* out = (float*)d_out;

    char* ws = (char*)d_ws;
    uint4*    DBh = (uint4*)ws;                         ws += (size_t)(N_DB / 32) * 128 * 16; // 4 MB
    float*    hdb = (float*)ws;                         ws += (size_t)N_DB * 4;               // 256 KB
    unsigned* cand = (unsigned*)ws;                     // 4096*384*4 = 6 MB  (total 10.25 MB)

    k_prep<<<N_DB / 256, 256, 0, stream>>>(DB, DBh, hdb);
    k_scan<<<(N_Q / 128) * NC, 256, 0, stream>>>(Q, DBh, hdb, cand);
    k_merge<<<N_Q / 4, 256, 0, stream>>>(Q, DB, AUX, cand, out);
}

// Round 10
// 137.590 us; speedup vs baseline: 5.1138x; 1.0092x over previous
//
#include <hip/hip_runtime.h>
#include <math.h>

#define N_Q   4096
#define N_DB  65536
#define DIM   32
#define KNN   5
#define NC    64                 // chunks
#define CH    (N_DB / NC)        // 1024 points per chunk
#define TS    128                // staged tile (points)
#define NSTG  (CH / TS)          // 8 stages per chunk
#define NSUB  (TS / 32)          // 4 subtiles per stage
#define NCAND (NC * 6)           // 384 candidates per query
#define BIAS  256.0f

typedef _Float16 half8  __attribute__((ext_vector_type(8)));
typedef __fp16   fp16x2 __attribute__((ext_vector_type(2)));
typedef float floatx16  __attribute__((ext_vector_type(16)));

union H8  { half8 h; uint4 u4; unsigned u[4]; };
union F16 { floatx16 v; float4 q4[4]; unsigned w[16]; };
union HU  { fp16x2 h2; unsigned u; };

__device__ __forceinline__ unsigned cvt2(float a, float b) {
    HU t; t.h2 = __builtin_amdgcn_cvt_pkrtz(a, b);
    return t.u;
}

__device__ __forceinline__ void ld_lds16(const void* g, void* l) {
    __builtin_amdgcn_global_load_lds((const __attribute__((address_space(1))) unsigned*)g,
                                     (__attribute__((address_space(3))) unsigned*)l, 16, 0, 0);
}
__device__ __forceinline__ void ld_lds4(const void* g, void* l) {
    __builtin_amdgcn_global_load_lds((const __attribute__((address_space(1))) unsigned*)g,
                                     (__attribute__((address_space(3))) unsigned*)l, 4, 0, 0);
}

// ---------------- kernel 0: fp32 db -> tile-major fp16 image + biased norms ----------------
// DBh: [tile=p>>5][kgroup 0..3][row=p&31][8 halves]  (2 KB per 32-pt tile)
__global__ __launch_bounds__(256) void k_prep(const float* __restrict__ DB,
                                              uint4* __restrict__ DBh,
                                              float* __restrict__ hdb) {
    int p = blockIdx.x * 256 + threadIdx.x;
    const float4* src = (const float4*)(DB + (size_t)p * DIM);
    float4 f[8]; float s = 0.f;
#pragma unroll
    for (int j = 0; j < 8; ++j) {
        f[j] = src[j];
        s += f[j].x * f[j].x + f[j].y * f[j].y + f[j].z * f[j].z + f[j].w * f[j].w;
    }
    hdb[p] = BIAS - 0.5f * s;
    int t = p >> 5, r = p & 31;
#pragma unroll
    for (int gi = 0; gi < 4; ++gi) {
        uint4 g;
        g.x = cvt2(f[2 * gi].x, f[2 * gi].y);
        g.y = cvt2(f[2 * gi].z, f[2 * gi].w);
        g.z = cvt2(f[2 * gi + 1].x, f[2 * gi + 1].y);
        g.w = cvt2(f[2 * gi + 1].z, f[2 * gi + 1].w);
        DBh[(size_t)t * 128 + gi * 32 + r] = g;
    }
}

// ---------------- kernel 1: MFMA scan + per-chunk approx top-6 ----------------
// 256 threads (4 waves) = 128-query tile x 1024-pt chunk; grid 32 x 64 = 2048 blocks.
// launch_bounds(256,6): arg2 = min BLOCKS/CU (R7/R9 evidence); 6 waves/SIMD ->
// ~85-reg combined V+A budget (true live set ~75). R9's (256,4) let the compiler
// expand to 128 combined regs -> only 4 blocks/CU resident (50% occupancy).
__global__ __launch_bounds__(256, 6) void k_scan(const float* __restrict__ Q,
                                                 const uint4* __restrict__ DBh,
                                                 const float* __restrict__ hdb,
                                                 unsigned* __restrict__ cand) {
    __shared__ char  dbs[2][8192];     // fp16 db stage (4 subtiles x 2 KB)
    __shared__ float hbs[2][TS];       // C-init values

    const int tid = threadIdx.x, lane = tid & 63, w = tid >> 6;   // w=0..3
    const int h = lane >> 5, qcol = lane & 31;
    const int chunk = blockIdx.x & (NC - 1);   // same-chunk blocks: stride 64 -> same XCD
    const int qb    = blockIdx.x >> 6;         // 0..31
    const int q     = qb * 128 + w * 32 + qcol;
    const int pbase = chunk * CH;

    // B-frags: convert this lane's query dims once
    const float* qp = Q + (size_t)q * DIM;
    float4 qa = *(const float4*)(qp + h * 8);
    float4 qb4 = *(const float4*)(qp + h * 8 + 4);
    float4 qc = *(const float4*)(qp + 16 + h * 8);
    float4 qd = *(const float4*)(qp + 16 + h * 8 + 4);
    H8 b1, b2;
    b1.u[0] = cvt2(qa.x, qa.y);   b1.u[1] = cvt2(qa.z, qa.w);
    b1.u[2] = cvt2(qb4.x, qb4.y); b1.u[3] = cvt2(qb4.z, qb4.w);
    b2.u[0] = cvt2(qc.x, qc.y);   b2.u[1] = cvt2(qc.z, qc.w);
    b2.u[2] = cvt2(qd.x, qd.y);   b2.u[3] = cvt2(qd.z, qd.w);

    // opaque VGPR mask -> pack is a single v_and_or_b32 (S2 = scalar id)
    unsigned maskv;
    asm("v_mov_b32 %0, 0xFFFFFC00" : "=v"(maskv));

    auto stage = [&](int buf, int t) {
        const char* s = (const char*)DBh + (size_t)pbase * 64 + (size_t)t * 8192
                        + w * 1024 + lane * 16;
        char* d = dbs[buf] + w * 1024;            // wave-uniform base; HW adds lane*16
        ld_lds16(s, d);
        ld_lds16(s + 4096, d + 4096);
        if (w < 2)                                 // waves 0,1 stage the 128 C-init floats
            ld_lds4(hdb + pbase + t * TS + w * 64 + lane,
                    (char*)&hbs[buf][0] + w * 256);
    };

    float tk[6];
#pragma unroll
    for (int r = 0; r < 6; ++r) tk[r] = 0.f;

    constexpr int ROWC[16] = {0,1,2,3, 8,9,10,11, 16,17,18,19, 24,25,26,27}; // bit 2 free (=h)

    stage(0, 0);
    for (int t = 0; t < NSTG; ++t) {
        __syncthreads();                           // drains buf(t) loads (issued a stage ago)
        if (t + 1 < NSTG) stage((t + 1) & 1, t + 1);
        const int buf = t & 1;
        const char* base = dbs[buf];
#pragma unroll
        for (int sub = 0; sub < NSUB; ++sub) {
            const char* tb = base + sub * 2048;
            H8 a1, a2;
            a1.u4 = *(const uint4*)(tb + h * 512 + (lane & 31) * 16);
            a2.u4 = *(const uint4*)(tb + 1024 + h * 512 + (lane & 31) * 16);
            F16 c0;
            const float* hb = &hbs[buf][sub * 32 + 4 * h];
            c0.q4[0] = *(const float4*)(hb + 0);
            c0.q4[1] = *(const float4*)(hb + 8);
            c0.q4[2] = *(const float4*)(hb + 16);
            c0.q4[3] = *(const float4*)(hb + 24);
            floatx16 acc = __builtin_amdgcn_mfma_f32_32x32x16_f16(a1.h, b1.h, c0.v, 0, 0, 0);
            acc = __builtin_amdgcn_mfma_f32_32x32x16_f16(a2.h, b2.h, acc, 0, 0, 0);
            // pack 10-bit chunk-local id (tile<<5 | rowc); h bit is OR-ed at chunk end
            F16 pk; pk.v = acc;
            const int meta = (t * NSUB + sub) << 5;      // wave-uniform (scalar pipe)
            float p[16];
#pragma unroll
            for (int r = 0; r < 16; ++r)
                p[r] = __uint_as_float((pk.w[r] & maskv) | (unsigned)(meta | ROWC[r]));
            // true top-2 of 16 (max/min tournament; L-combines fold to v_max3)
            float hi[8], lo[8];
#pragma unroll
            for (int i = 0; i < 8; ++i) { hi[i] = fmaxf(p[2*i], p[2*i+1]); lo[i] = fminf(p[2*i], p[2*i+1]); }
            float H4[4], L4[4];
#pragma unroll
            for (int i = 0; i < 4; ++i) {
                H4[i] = fmaxf(hi[2*i], hi[2*i+1]);
                L4[i] = fmaxf(fmaxf(lo[2*i], lo[2*i+1]), fminf(hi[2*i], hi[2*i+1]));
            }
            float H2[2], L2[2];
#pragma unroll
            for (int i = 0; i < 2; ++i) {
                H2[i] = fmaxf(H4[2*i], H4[2*i+1]);
                L2[i] = fmaxf(fmaxf(L4[2*i], L4[2*i+1]), fminf(H4[2*i], H4[2*i+1]));
            }
            float c1 = fmaxf(H2[0], H2[1]);
            float c2 = fmaxf(fmaxf(L2[0], L2[1]), fminf(H2[0], H2[1]));
            // merge sorted pair (c1 >= c2) into sorted tk[6] via merge-path:
            // out_i = max(a_i, min(a_{i-1}, c1), min(a_{i-2}, c2)) — 15 ops,
            // parallel (vs R9's 22-op, 12-deep serial chain). Exact.
            {
                float m01 = fminf(tk[0], c1), m02 = fminf(tk[1], c1);
                float m03 = fminf(tk[2], c1), m04 = fminf(tk[3], c1);
                float m05 = fminf(tk[4], c1);
                float m12 = fminf(tk[0], c2), m13 = fminf(tk[1], c2);
                float m14 = fminf(tk[2], c2), m15 = fminf(tk[3], c2);
                tk[0] = fmaxf(tk[0], c1);
                tk[1] = fmaxf(fmaxf(tk[1], m01), c2);
                tk[2] = fmaxf(fmaxf(tk[2], m02), m12);
                tk[3] = fmaxf(fmaxf(tk[3], m03), m13);
                tk[4] = fmaxf(fmaxf(tk[4], m04), m14);
                tk[5] = fmaxf(fmaxf(tk[5], m05), m15);
            }
        }
    }

    // set the h bit (bit 2 of id field) on the 6 survivors, once per chunk
#pragma unroll
    for (int r = 0; r < 6; ++r)
        tk[r] = __uint_as_float(__float_as_uint(tk[r]) | (unsigned)(h << 2));

    // cross-half merge: SNAPSHOT partner's list before mutating (R6 hazard fix)
    float other[6];
#pragma unroll
    for (int i = 0; i < 6; ++i) other[i] = __shfl_xor(tk[i], 32, 64);
#pragma unroll
    for (int i = 0; i < 6; ++i) {
        float val = other[i];
#pragma unroll
        for (int j = 0; j < 6; ++j) { float mx = fmaxf(tk[j], val); val = fminf(tk[j], val); tk[j] = mx; }
    }
    if (h == 0) {
        unsigned* dst = cand + ((size_t)q * NC + chunk) * 6;
#pragma unroll
        for (int r = 0; r < 6; ++r) dst[r] = __float_as_uint(tk[r]);
    }
}

// ---------------- kernel 2: global approx top-12, exact rescore, top-5, blend ----------------
__global__ __launch_bounds__(256) void k_merge(const float* __restrict__ Q,
                                               const float* __restrict__ DB,
                                               const float* __restrict__ AUX,
                                               const unsigned* __restrict__ cand,
                                               float* __restrict__ out) {
    const int tid = threadIdx.x, lane = tid & 63, w = tid >> 6;
    const int q = blockIdx.x * 4 + w;

    const unsigned* cq = cand + (size_t)q * NCAND + (size_t)lane * 6;
    float cur[6];
#pragma unroll
    for (int r = 0; r < 6; ++r) cur[r] = __uint_as_float(cq[r]);

    float wv[12]; int wl[12];
#pragma unroll
    for (int r = 0; r < 12; ++r) {
        float bv = cur[0]; int bl = lane;
#pragma unroll
        for (int off = 32; off >= 1; off >>= 1) {
            float ov = __shfl_xor(bv, off, 64);
            int   ol = __shfl_xor(bl, off, 64);
            if (ov > bv || (ov == bv && ol < bl)) { bv = ov; bl = ol; }
        }
        wv[r] = bv; wl[r] = bl;
        if (bl == lane) {
#pragma unroll
            for (int s = 0; s < 5; ++s) cur[s] = cur[s + 1];
            cur[5] = -1.f;
        }
    }

    float dist = 1e30f; int dbi = 0x7fffffff;
    if (lane < 12) {
        unsigned u = __float_as_uint(wv[lane]) & 1023u;   // chunk-local point id
        dbi = wl[lane] * CH + (int)u;
        const float4* dp = (const float4*)(DB + (size_t)dbi * DIM);
        const float4* qp = (const float4*)(Q + (size_t)q * DIM);
        float dot = 0.f, qs = 0.f, ds = 0.f;
#pragma unroll
        for (int j = 0; j < DIM / 4; ++j) {
            float4 a = qp[j], d = dp[j];
            dot += a.x * d.x + a.y * d.y + a.z * d.z + a.w * d.w;
            qs  += a.x * a.x + a.y * a.y + a.z * a.z + a.w * a.w;
            ds  += d.x * d.x + d.y * d.y + d.z * d.z + d.w * d.w;
        }
        dist = sqrtf(fmaxf(qs + ds - 2.f * dot, 0.f));
    }
    float wd[KNN]; int wi[KNN];
#pragma unroll
    for (int r = 0; r < KNN; ++r) {
        float bd = dist; int bi = dbi;
#pragma unroll
        for (int off = 32; off >= 1; off >>= 1) {
            float od = __shfl_xor(bd, off, 64);
            int   oi = __shfl_xor(bi, off, 64);
            if (od < bd || (od == bd && oi < bi)) { bd = od; bi = oi; }
        }
        wd[r] = bd; wi[r] = bi;
        if (dist == bd && dbi == bi) dist = 1e30f;
    }
    float ww[KNN], W = 0.f;
#pragma unroll
    for (int r = 0; r < KNN; ++r) { ww[r] = 1.f / (wd[r] + 1e-6f); W += ww[r]; }
    if (lane < DIM) {
        float o = 0.f;
#pragma unroll
        for (int r = 0; r < KNN; ++r) o += ww[r] * AUX[(size_t)wi[r] * DIM + lane];
        out[(size_t)q * DIM + lane] = o / W;
    }
}

// ---------------- launch ----------------
extern "C" void kernel_launch(void* const* d_in, const int* in_sizes, int n_in,
                              void* d_out, int out_size, void* d_ws, size_t ws_size,
                              hipStream_t stream) {
    const float* Q   = (const float*)d_in[0];
    const float* DB  = (const float*)d_in[1];
    const float* AUX = (const float*)d_in[2];
    float* out = (float*)d_out;

    char* ws = (char*)d_ws;
    uint4*    DBh = (uint4*)ws;                         ws += (size_t)(N_DB / 32) * 128 * 16; // 4 MB
    float*    hdb = (float*)ws;                         ws += (size_t)N_DB * 4;               // 256 KB
    unsigned* cand = (unsigned*)ws;                     // 4096*384*4 = 6 MB  (total 10.25 MB)

    k_prep<<<N_DB / 256, 256, 0, stream>>>(DB, DBh, hdb);
    k_scan<<<(N_Q / 128) * NC, 256, 0, stream>>>(Q, DBh, hdb, cand);
    k_merge<<<N_Q / 4, 256, 0, stream>>>(Q, DB, AUX, cand, out);
}